// Round 9
// baseline (283.550 us; speedup 1.0000x reference)
//
#include <hip/hip_runtime.h>
#include <math.h>

constexpr int BB = 4, CH = 512, NN = 4096, NHEADS = 4, NGROUPS = 32, HCH = 128;
constexpr float EPS = 1e-5f;
constexpr float SCALE = 0.08838834764831845f;  // 128^-0.5
constexpr float LOG2E = 1.4426950408889634f;
constexpr float QSCALE = SCALE * LOG2E;        // fold exp->exp2 domain into Q
constexpr float THR = 11.541560327111707f;     // 8 * log2(e)

typedef short bf16x8 __attribute__((ext_vector_type(8)));
typedef float f32x4 __attribute__((ext_vector_type(4)));
typedef float f32x16 __attribute__((ext_vector_type(16)));

__device__ __forceinline__ float bf2f(unsigned short u) {
    unsigned int x = ((unsigned int)u) << 16;
    float f; __builtin_memcpy(&f, &x, 4); return f;
}
__device__ __forceinline__ unsigned short f2bf(float f) {
    unsigned int x; __builtin_memcpy(&x, &f, 4);
    x += 0x7fff + ((x >> 16) & 1);          // RNE
    return (unsigned short)(x >> 16);
}
// RNE pack of 2 f32 -> 2 bf16 in one u32 (no builtin on gfx950; m240)
__device__ __forceinline__ unsigned int cvtpk(float lo, float hi) {
    unsigned int r;
    asm("v_cvt_pk_bf16_f32 %0, %1, %2" : "=v"(r) : "v"(lo), "v"(hi));
    return r;
}
// raw 2^x (exp2f without fast-math lowers to a multi-instr ocml fixup path)
__device__ __forceinline__ float fexp2(float x) {
    float r; asm("v_exp_f32 %0, %1" : "=v"(r) : "v"(x)); return r;
}

// async global->LDS, 16B per lane; LDS dest = wave-uniform base + lane*16
__device__ __forceinline__ void gld16(const void* g, void* l) {
    __builtin_amdgcn_global_load_lds(
        (const __attribute__((address_space(1))) void*)g,
        (__attribute__((address_space(3))) void*)l, 16, 0, 0);
}

// ---------------------------------------------------------------------------
// Fused prep: weight convert (blocks 0..1023) + GroupNorm partial stats
// (blocks 1024..1535, atomic accumulate into pre-zeroed stats).
// ---------------------------------------------------------------------------
__global__ __launch_bounds__(256) void prep_kernel(
    const float* __restrict__ qkv_w, const float* __restrict__ out_w,
    const float* __restrict__ x,
    unsigned short* __restrict__ wq_bf, unsigned short* __restrict__ wo_bf,
    float* __restrict__ stats)
{
    int bid = blockIdx.x;
    if (bid < 1024) {
        int i4 = bid * 256 + threadIdx.x;          // float4 index
        if (i4 < 196608) {                         // 1536*512/4
            float4 w = ((const float4*)qkv_w)[i4];
            int row = i4 >> 7;
            float sc = (row < 512) ? QSCALE : 1.0f;
            ushort4 o = { f2bf(w.x * sc), f2bf(w.y * sc), f2bf(w.z * sc), f2bf(w.w * sc) };
            *(ushort4*)&wq_bf[(size_t)i4 * 4] = o;
        } else {
            int j4 = i4 - 196608;
            float4 w = ((const float4*)out_w)[j4];
            ushort4 o = { f2bf(w.x), f2bf(w.y), f2bf(w.z), f2bf(w.w) };
            *(ushort4*)&wo_bf[(size_t)j4 * 4] = o;
        }
        return;
    }
    // ---- GN partial stats: 512 blocks, 4 partials per (b,g) ----
    const int CPG = CH / NGROUPS;              // 16
    int gb = bid - 1024;
    int bg = gb >> 2, part = gb & 3;
    int b = bg / NGROUPS, g = bg % NGROUPS;
    const size_t base = ((size_t)b * CH + (size_t)g * CPG) * NN
                      + (size_t)part * (CPG * NN / 4);
    const int total4 = CPG * NN / 16;          // 4096 float4 per part
    int tid = threadIdx.x;

    const float4* x4 = (const float4*)(x + base);
    float sum = 0.f, sumsq = 0.f;
    for (int i = tid; i < total4; i += 256) {
        float4 v = x4[i];
        sum   += v.x + v.y + v.z + v.w;
        sumsq += v.x*v.x + v.y*v.y + v.z*v.z + v.w*v.w;
    }
    for (int off = 32; off > 0; off >>= 1) {
        sum   += __shfl_down(sum, off);
        sumsq += __shfl_down(sumsq, off);
    }
    __shared__ float s_sum[4], s_sq[4];
    int wid = tid >> 6, lane = tid & 63;
    if (lane == 0) { s_sum[wid] = sum; s_sq[wid] = sumsq; }
    __syncthreads();
    if (tid == 0) {
        float ts = 0.f, tq = 0.f;
        for (int i = 0; i < 4; i++) { ts += s_sum[i]; tq += s_sq[i]; }
        atomicAdd(&stats[bg * 2 + 0], ts);
        atomicAdd(&stats[bg * 2 + 1], tq);
    }
}

// ---------------------------------------------------------------------------
// Transpose + inline GroupNorm apply (mean/rstd computed from raw sums):
//   xnT[b][n][c] = GN(x) bf16 ;  xT[b][n][c] = x bf16 (residual)
// ---------------------------------------------------------------------------
__global__ __launch_bounds__(256) void t1_kernel(
    const float* __restrict__ x, const float2* __restrict__ stats,
    const float* __restrict__ gamma, const float* __restrict__ beta,
    unsigned short* __restrict__ xnT, unsigned short* __restrict__ xT)
{
    __shared__ alignas(16) short Tn[64 * 80];
    __shared__ alignas(16) short Tr[64 * 80];
    int n0 = blockIdx.x * 64, c0 = blockIdx.y * 64, b = blockIdx.z;
    int tid = threadIdx.x;
    const float inv = 1.0f / 65536.0f;

    #pragma unroll
    for (int i = 0; i < 4; ++i) {
        int idx = tid + i * 256; int cl = idx >> 4, nq = idx & 15;
        int c = c0 + cl;
        float2 st = stats[b * NGROUPS + (c >> 4)];
        float mean = st.x * inv;
        float var  = st.y * inv - mean * mean;
        float rstd = rsqrtf(var + EPS);
        float gm = gamma[c], bt = beta[c];
        float4 f = *(const float4*)&x[((size_t)(b * CH + c)) * NN + n0 + nq * 4];
        float e0 = f.x, e1 = f.y, e2 = f.z, e3 = f.w;
        Tr[(nq * 4 + 0) * 80 + cl] = (short)f2bf(e0);
        Tr[(nq * 4 + 1) * 80 + cl] = (short)f2bf(e1);
        Tr[(nq * 4 + 2) * 80 + cl] = (short)f2bf(e2);
        Tr[(nq * 4 + 3) * 80 + cl] = (short)f2bf(e3);
        Tn[(nq * 4 + 0) * 80 + cl] = (short)f2bf((e0 - mean) * rstd * gm + bt);
        Tn[(nq * 4 + 1) * 80 + cl] = (short)f2bf((e1 - mean) * rstd * gm + bt);
        Tn[(nq * 4 + 2) * 80 + cl] = (short)f2bf((e2 - mean) * rstd * gm + bt);
        Tn[(nq * 4 + 3) * 80 + cl] = (short)f2bf((e3 - mean) * rstd * gm + bt);
    }
    __syncthreads();
    #pragma unroll
    for (int i = 0; i < 2; ++i) {
        int idx = tid + i * 256; int n = idx >> 3, ck = idx & 7;
        size_t gidx = ((size_t)(b * NN + n0 + n)) * CH + c0 + ck * 8;
        *(uint4*)&xnT[gidx] = *(uint4*)&Tn[n * 80 + ck * 8];
        *(uint4*)&xT[gidx]  = *(uint4*)&Tr[n * 80 + ck * 8];
    }
}

// ---------------------------------------------------------------------------
// MFMA GEMM: out[b][m][n] = A[m][:]·Bt[b][n][:] + bias
// Main loop: global_load_lds double-buffered staging, linear LDS dest
// [128][64] bf16, pre-swizzled global source L = s^(r&7), XOR-swizzled
// ds_read_b128, ONE barrier/K-step.  (Round-7: this cut gemm0 ~2x.)
// ---------------------------------------------------------------------------
template<int MODE>
__global__ __launch_bounds__(256) void gemm_kernel(
    const unsigned short* __restrict__ A,    // [M][512] bf16
    const unsigned short* __restrict__ Bt,   // [B][4096][512] bf16
    const float* __restrict__ bias,          // [M]
    unsigned short* __restrict__ qT, unsigned short* __restrict__ kT,
    unsigned short* __restrict__ v, float* __restrict__ out)
{
    __shared__ alignas(16) short smem[2][2][128 * 64];   // [buf][A|B], 64KB
    short* Es = (short*)smem;                            // MODE0 epi: 128*132 shorts
    float* Ef = (float*)smem;                            // MODE1 epi: 128*66 floats

    constexpr int GY = (MODE == 0) ? 12 : 4;
    int lin = blockIdx.x + 32 * (blockIdx.y + GY * blockIdx.z);
    constexpr int CPX = 32 * GY * 4 / 8;
    int wg = (lin & 7) * CPX + (lin >> 3);
    const int n0 = (wg % 32) * 128;
    const int m0 = ((wg / 32) % GY) * 128;
    const int b  = wg / (32 * GY);

    const int tid = threadIdx.x;
    const int wid = tid >> 6, l = tid & 63, lr = l & 15, lk = l >> 4;
    const int wm = (wid & 1) * 64, wn = (wid >> 1) * 64;
    const unsigned short* Bb = Bt + (size_t)b * NN * CH;

    // staging: 16KB/tensor = 16 x 1KB chunks, 4 chunks/wave per tensor.
    int rr[4], LL[4], ch[4];
    #pragma unroll
    for (int i = 0; i < 4; ++i) {
        ch[i] = (wid * 4 + i) * 1024;
        int li = ch[i] + l * 16;
        int r = li >> 7, s = (li >> 4) & 7;
        rr[i] = r; LL[i] = s ^ (r & 7);
    }

    #define GSTAGE(buf, k0) do {                                                   \
        _Pragma("unroll")                                                          \
        for (int i = 0; i < 4; ++i) {                                              \
            gld16(&A [((size_t)(m0 + rr[i])) * CH + (k0) + LL[i] * 8],             \
                  (char*)&smem[buf][0][0] + ch[i]);                                \
            gld16(&Bb[((size_t)(n0 + rr[i])) * CH + (k0) + LL[i] * 8],             \
                  (char*)&smem[buf][1][0] + ch[i]);                                \
        }                                                                          \
    } while (0)

    f32x4 acc[4][4];
    #pragma unroll
    for (int i = 0; i < 4; ++i)
        #pragma unroll
        for (int j = 0; j < 4; ++j) acc[i][j] = (f32x4){0.f, 0.f, 0.f, 0.f};

    GSTAGE(0, 0);
    __syncthreads();   // drains vmcnt -> tile 0 staged

    int cur = 0;
    for (int ks = 0; ks < 8; ++ks) {
        if (ks < 7) GSTAGE(cur ^ 1, (ks + 1) * 64);   // in flight during compute
        const char* As = (const char*)&smem[cur][0][0];
        const char* Bs = (const char*)&smem[cur][1][0];
        #pragma unroll
        for (int kh = 0; kh < 2; ++kh) {
            const int sw = ((kh * 4 + lk) ^ (lr & 7)) << 4;
            bf16x8 af[4], bfr[4];
            #pragma unroll
            for (int t = 0; t < 4; ++t) {
                af[t]  = *(const bf16x8*)(As + (wm + t * 16 + lr) * 128 + sw);
                bfr[t] = *(const bf16x8*)(Bs + (wn + t * 16 + lr) * 128 + sw);
            }
            #pragma unroll
            for (int mt = 0; mt < 4; ++mt)
                #pragma unroll
                for (int nt = 0; nt < 4; ++nt)
                    acc[mt][nt] = __builtin_amdgcn_mfma_f32_16x16x32_bf16(
                        af[mt], bfr[nt], acc[mt][nt], 0, 0, 0);
        }
        __syncthreads();   // drains vmcnt (next tile) + guards buffer reuse
        cur ^= 1;
    }
    #undef GSTAGE

    if (MODE == 0) {
        const bool isV = (m0 >= 1024);
        #pragma unroll
        for (int mt = 0; mt < 4; ++mt) {
            int mbase = m0 + wm + mt * 16 + lk * 4;
            int ml = wm + mt * 16 + lk * 4;
            float bsc = (m0 < 512) ? QSCALE : 1.0f;
            #pragma unroll
            for (int nt = 0; nt < 4; ++nt) {
                int nl = wn + nt * 16 + lr;
                f32x4 vv = acc[mt][nt];
                if (!isV) {
                    ushort4 o;
                    o.x = f2bf(vv[0] + bias[mbase + 0] * bsc);
                    o.y = f2bf(vv[1] + bias[mbase + 1] * bsc);
                    o.z = f2bf(vv[2] + bias[mbase + 2] * bsc);
                    o.w = f2bf(vv[3] + bias[mbase + 3] * bsc);
                    *(ushort4*)&Es[nl * 132 + ml] = o;
                } else {
                    #pragma unroll
                    for (int j = 0; j < 4; ++j)
                        Es[(ml + j) * 132 + nl] = (short)f2bf(vv[j] + bias[mbase + j]);
                }
            }
        }
        __syncthreads();
        int r16 = tid >> 4, c16 = tid & 15;
        if (!isV) {
            unsigned short* dst;
            if (m0 < 512) dst = qT + (((size_t)(b * 4 + (m0 >> 7))) * NN + n0) * 128;
            else          dst = kT + (((size_t)(b * 4 + ((m0 - 512) >> 7))) * NN + n0) * 128;
            #pragma unroll
            for (int p = 0; p < 8; ++p) {
                int nl = p * 16 + r16;
                uint4 w = *(const uint4*)&Es[nl * 132 + c16 * 8];
                *(uint4*)&dst[(size_t)nl * 128 + c16 * 8] = w;
            }
        } else {
            unsigned short* dst = v + ((size_t)(b * 512 + (m0 - 1024)) * NN) + n0;
            #pragma unroll
            for (int p = 0; p < 8; ++p) {
                int ml = p * 16 + r16;
                uint4 w = *(const uint4*)&Es[ml * 132 + c16 * 8];
                *(uint4*)&dst[(size_t)ml * NN + c16 * 8] = w;
            }
        }
    } else {
        // fp32 out: LDS transpose in 2 n-halves -> full 256B-row float4 stores
        for (int half = 0; half < 2; ++half) {
            __syncthreads();
            if ((wn >> 6) == half) {
                #pragma unroll
                for (int mt = 0; mt < 4; ++mt) {
                    int ml = wm + mt * 16 + lk * 4;
                    int mbase = m0 + ml;
                    #pragma unroll
                    for (int nt = 0; nt < 4; ++nt) {
                        int nl = nt * 16 + lr;          // 0..63 within half
                        f32x4 vv = acc[mt][nt];
                        #pragma unroll
                        for (int j = 0; j < 4; ++j)
                            Ef[(ml + j) * 66 + nl] = vv[j] + bias[mbase + j];
                    }
                }
            }
            __syncthreads();
            #pragma unroll
            for (int i = 0; i < 8; ++i) {
                int idx = tid + i * 256;                // 0..2047 float4s
                int r = idx >> 4, c4 = idx & 15;
                float4 w = *(const float4*)&Ef[r * 66 + c4 * 4];
                *(float4*)&out[((size_t)(b * CH + m0 + r)) * NN + n0 + half * 64 + c4 * 4] = w;
            }
        }
    }
}

// ---------------------------------------------------------------------------
// Flash attention, 32x32 MFMA + in-register P (T12) + ones-MFMA denominator.
// RESTRUCTURED (m114 inter-block overlap): 128-thread / 2-WAVE blocks,
// SINGLE-buffered K/V (32KB LDS) -> 4 independent blocks/CU.  Barriers now
// span 2 waves and each CU has 3 other blocks to cover stage/drain stalls
// (the 4-wave dbuf structure measured ~40% stall with nothing saturated).
// K tile: 64 rows x 256B; V tile: 64 rows x 256B (d, d+64 pairs); 4-bit XOR
// swizzle both sides (2-way, free).  grid 1024 x 128 thr, XCD-swizzled.
// ---------------------------------------------------------------------------
__global__ __launch_bounds__(128, 2) void attn_kernel(
    const unsigned short* __restrict__ qT,  // [BH][N][128] (pre-scaled by SCALE*log2e)
    const unsigned short* __restrict__ kT,  // [BH][N][128]
    const unsigned short* __restrict__ vg,  // [BH*128][N]
    const unsigned short* __restrict__ xT,  // [B][N][512] residual bf16
    unsigned short* __restrict__ aoT)       // [B][N][512]
{
    __shared__ alignas(16) short Ks[64 * 128];   // 16KB: 64 rows x 256B
    __shared__ alignas(16) short Vs[64 * 128];   // 16KB: 64 rows x 256B (d,d+64 pairs)

    // bijective XCD swizzle: 1024 wgs, 8 XCDs -> 128 consecutive wgs per XCD
    // (= 2 full (b,h) panels per XCD -> 4MB K/V, L2-resident)
    int lin_id = blockIdx.x + 64 * (blockIdx.y + 4 * blockIdx.z);
    int wg = (lin_id & 7) * 128 + (lin_id >> 3);
    const int n0 = (wg & 63) * 64;
    const int h  = (wg >> 6) & 3;
    const int b  = wg >> 8;

    const int bh = b * 4 + h;
    const int tid = threadIdx.x, wid = tid >> 6, l = tid & 63;
    const int lq = l & 31, hi = l >> 5;
    const int wq0 = wid * 32;
    const int swz4 = (l & 15) << 4;             // read-side XOR, bits 4-7
    const unsigned short* Qg = qT + (size_t)bh * NN * 128;
    const unsigned short* Kg = kT + (size_t)bh * NN * 128;
    const unsigned short* Vg = vg + (size_t)bh * 128 * NN;

    // staging: 16 x 1KB chunks per tensor, 8 chunks/wave per tensor.
    // addresses recomputed per STAGE (keeps VGPR under the (128,2) cap).
    #define STAGE(m0k) do {                                                        \
        _Pragma("unroll")                                                          \
        for (int i = 0; i < 8; ++i) {                                              \
            int li = (wid * 8 + i) * 1024 + l * 16;                                \
            int r = li >> 8, s = (li >> 4) & 15;                                   \
            int L = s ^ (r & 15);                                                  \
            gld16(&Kg[(size_t)((m0k) + r) * 128 + L * 8], (char*)Ks + li);         \
            gld16(&Vg[(size_t)(r + 64 * (L >> 3)) * NN + (m0k) + (L & 7) * 8],     \
                  (char*)Vs + li);                                                 \
        }                                                                          \
    } while (0)

    // ---- Q -> registers ----
    bf16x8 qr[8];
    #pragma unroll
    for (int dk = 0; dk < 8; ++dk)
        qr[dk] = *(const bf16x8*)&Qg[((size_t)(n0 + wq0 + lq)) * 128 + dk * 16 + hi * 8];

    bf16x8 vone;
    #pragma unroll
    for (int j = 0; j < 8; ++j) vone[j] = (short)0x3F80;   // bf16 1.0

    f32x16 ov[4], ovs;
    #pragma unroll
    for (int dt = 0; dt < 4; ++dt)
        #pragma unroll
        for (int r = 0; r < 16; ++r) ov[dt][r] = 0.f;
    #pragma unroll
    for (int r = 0; r < 16; ++r) ovs[r] = 0.f;
    float mrun = -1e30f;

    for (int t = 0; t < 64; ++t) {
        STAGE(t * 64);
        __syncthreads();   // drains vmcnt -> tile staged (2-wave barrier)

        // ---- QK^T (32x32x16): col = q = lq, row k-local = (reg&3)+8*(reg>>2)+4*hi
        f32x16 s0, s1;
        #pragma unroll
        for (int r = 0; r < 16; ++r) { s0[r] = 0.f; s1[r] = 0.f; }
        __builtin_amdgcn_s_setprio(1);
        #pragma unroll
        for (int dk = 0; dk < 8; ++dk) {
            bf16x8 k0 = *(const bf16x8*)((const char*)Ks + (lq)      * 256 + ((dk * 32 + hi * 16) ^ swz4));
            bf16x8 k1 = *(const bf16x8*)((const char*)Ks + (32 + lq) * 256 + ((dk * 32 + hi * 16) ^ swz4));
            s0 = __builtin_amdgcn_mfma_f32_32x32x16_bf16(k0, qr[dk], s0, 0, 0, 0);
            s1 = __builtin_amdgcn_mfma_f32_32x32x16_bf16(k1, qr[dk], s1, 0, 0, 0);
        }
        __builtin_amdgcn_s_setprio(0);

        // ---- in-register online softmax (log2 domain) ----
        float m8[8];
        #pragma unroll
        for (int r = 0; r < 8; ++r)
            m8[r] = fmaxf(fmaxf(s0[r], s0[r + 8]), fmaxf(s1[r], s1[r + 8]));
        float t0 = fmaxf(fmaxf(m8[0], m8[1]), m8[2]);
        float t1_ = fmaxf(fmaxf(m8[3], m8[4]), m8[5]);
        float t2 = fmaxf(fmaxf(m8[6], m8[7]), t0);
        float pm = fmaxf(t1_, t2);
        pm = fmaxf(pm, __shfl_xor(pm, 32));

        int defer = (pm - mrun) <= THR;
        if (!__all(defer)) {
            float mnew = fmaxf(mrun, pm);
            float corr = fexp2(mrun - mnew);
            mrun = mnew;
            #pragma unroll
            for (int dt = 0; dt < 4; ++dt)
                #pragma unroll
                for (int r = 0; r < 16; ++r) ov[dt][r] *= corr;
            #pragma unroll
            for (int r = 0; r < 16; ++r) ovs[r] *= corr;
        }
        #pragma unroll
        for (int r = 0; r < 16; ++r) s0[r] = fexp2(s0[r] - mrun);
        #pragma unroll
        for (int r = 0; r < 16; ++r) s1[r] = fexp2(s1[r] - mrun);

        // ---- P -> bf16 + in-register redistribution (T12) ----
        unsigned int u0[8], u1[8];
        #pragma unroll
        for (int m = 0; m < 8; ++m) {
            u0[m] = cvtpk(s0[2 * m], s0[2 * m + 1]);
            u1[m] = cvtpk(s1[2 * m], s1[2 * m + 1]);
        }
        bf16x8 pf[4];
        #pragma unroll
        for (int kt = 0; kt < 2; ++kt)
            #pragma unroll
            for (int hh = 0; hh < 2; ++hh) {
                const unsigned int* u = kt ? u1 : u0;
                unsigned int w0 = u[4*hh + 0], w2 = u[4*hh + 2];
                unsigned int w1 = u[4*hh + 1], w3 = u[4*hh + 3];
                asm("v_permlane32_swap_b32 %0, %1" : "+v"(w0), "+v"(w2));
                asm("v_permlane32_swap_b32 %0, %1" : "+v"(w1), "+v"(w3));
                unsigned int w[4] = { w0, w1, w2, w3 };
                bf16x8 p; __builtin_memcpy(&p, w, 16);
                pf[kt * 2 + hh] = p;
            }

        // ---- PV (32x32x16): ov[dt] += V^T-tile · P ;  ovs += 1^T · P ----
        __builtin_amdgcn_s_setprio(1);
        #pragma unroll
        for (int dt = 0; dt < 4; ++dt)
            #pragma unroll
            for (int kt2 = 0; kt2 < 4; ++kt2) {
                bf16x8 vf = *(const bf16x8*)((const char*)Vs + ((dt & 1) * 32 + lq) * 256 +
                                             ((((dt >> 1) * 8 + kt2 * 2 + hi) << 4) ^ swz4));
                ov[dt] = __builtin_amdgcn_mfma_f32_32x32x16_bf16(vf, pf[kt2], ov[dt], 0, 0, 0);
            }
        #pragma unroll
        for (int kt2 = 0; kt2 < 4; ++kt2)
            ovs = __builtin_amdgcn_mfma_f32_32x32x16_bf16(vone, pf[kt2], ovs, 0, 0, 0);
        __builtin_amdgcn_s_setprio(0);

        __syncthreads();   // all reads done before next STAGE overwrites
    }
    #undef STAGE

    // ---- epilogue: normalize, add residual, store aoT ----
    float linv = 1.0f / ovs[0];    // every C-row of ovs = sum_kv P[kv][lq]
    const int n = n0 + wq0 + lq;
    #pragma unroll
    for (int dt = 0; dt < 4; ++dt)
        #pragma unroll
        for (int m = 0; m < 4; ++m) {
            int d = dt * 32 + m * 8 + hi * 4;
            size_t gidx = ((size_t)(b * NN + n)) * CH + h * 128 + d;
            unsigned short xv[4];
            *(ushort4*)xv = *(const ushort4*)&xT[gidx];
            unsigned int w0 = cvtpk(ov[dt][4*m + 0] * linv + bf2f(xv[0]),
                                    ov[dt][4*m + 1] * linv + bf2f(xv[1]));
            unsigned int w1 = cvtpk(ov[dt][4*m + 2] * linv + bf2f(xv[2]),
                                    ov[dt][4*m + 3] * linv + bf2f(xv[3]));
            unsigned long long wv = (unsigned long long)w0 |
                                    ((unsigned long long)w1 << 32);
            *(unsigned long long*)&aoT[gidx] = wv;
        }
}

// ---------------------------------------------------------------------------
extern "C" void kernel_launch(void* const* d_in, const int* in_sizes, int n_in,
                              void* d_out, int out_size, void* d_ws, size_t ws_size,
                              hipStream_t stream) {
    const float* x      = (const float*)d_in[0];
    const float* gamma  = (const float*)d_in[1];
    const float* beta   = (const float*)d_in[2];
    const float* qkv_w  = (const float*)d_in[3];
    const float* qkv_b  = (const float*)d_in[4];
    const float* out_w  = (const float*)d_in[5];
    const float* out_b  = (const float*)d_in[6];
    float* out = (float*)d_out;

    char* ws = (char*)d_ws;
    const size_t SZ = (size_t)BB * CH * NN * 2;     // 16 MB per bf16 tensor
    unsigned short* xnT   = (unsigned short*)(ws);
    unsigned short* xT    = (unsigned short*)(ws + SZ);
    unsigned short* qT    = (unsigned short*)(ws + 2 * SZ);
    unsigned short* kT    = (unsigned short*)(ws + 3 * SZ);
    unsigned short* vbuf  = (unsigned short*)(ws + 4 * SZ);
    unsigned short* aoT   = (unsigned short*)(ws + 5 * SZ);
    unsigned short* wq_bf = (unsigned short*)(ws + 6 * SZ);
    unsigned short* wo_bf = (unsigned short*)(ws + 6 * SZ + (size_t)1536 * 512 * 2);
    float* stats = (float*)(ws + 6 * SZ + (size_t)2048 * 512 * 2);

    hipMemsetAsync(stats, 0, 256 * sizeof(float), stream);
    prep_kernel<<<dim3(1536), 256, 0, stream>>>(qkv_w, out_w, x, wq_bf, wo_bf, stats);
    t1_kernel<<<dim3(NN / 64, CH / 64, BB), 256, 0, stream>>>(
        x, (const float2*)stats, gamma, beta, xnT, xT);
    gemm_kernel<0><<<dim3(NN / 128, 1536 / 128, BB), 256, 0, stream>>>(
        wq_bf, xnT, qkv_b, qT, kT, vbuf, nullptr);
    attn_kernel<<<dim3(NN / 64, NHEADS, BB), 128, 0, stream>>>(qT, kT, vbuf, xT, aoT);
    gemm_kernel<1><<<dim3(NN / 128, CH / 128, BB), 256, 0, stream>>>(
        wo_bf, aoT, out_b, nullptr, nullptr, nullptr, out);
}

// Round 10
// 259.228 us; speedup vs baseline: 1.0938x; 1.0938x over previous
//
#include <hip/hip_runtime.h>
#include <math.h>

constexpr int BB = 4, CH = 512, NN = 4096, NHEADS = 4, NGROUPS = 32, HCH = 128;
constexpr float EPS = 1e-5f;
constexpr float SCALE = 0.08838834764831845f;  // 128^-0.5
constexpr float LOG2E = 1.4426950408889634f;
constexpr float QSCALE = SCALE * LOG2E;        // fold exp->exp2 domain into Q
constexpr float THR = 11.541560327111707f;     // 8 * log2(e)

typedef short bf16x8 __attribute__((ext_vector_type(8)));
typedef float f32x4 __attribute__((ext_vector_type(4)));
typedef float f32x16 __attribute__((ext_vector_type(16)));

__device__ __forceinline__ float bf2f(unsigned short u) {
    unsigned int x = ((unsigned int)u) << 16;
    float f; __builtin_memcpy(&f, &x, 4); return f;
}
__device__ __forceinline__ unsigned short f2bf(float f) {
    unsigned int x; __builtin_memcpy(&x, &f, 4);
    x += 0x7fff + ((x >> 16) & 1);          // RNE
    return (unsigned short)(x >> 16);
}
// RNE pack of 2 f32 -> 2 bf16 in one u32 (no builtin on gfx950; m240)
__device__ __forceinline__ unsigned int cvtpk(float lo, float hi) {
    unsigned int r;
    asm("v_cvt_pk_bf16_f32 %0, %1, %2" : "=v"(r) : "v"(lo), "v"(hi));
    return r;
}
// raw 2^x (exp2f without fast-math lowers to a multi-instr ocml fixup path)
__device__ __forceinline__ float fexp2(float x) {
    float r; asm("v_exp_f32 %0, %1" : "=v"(r) : "v"(x)); return r;
}

// async global->LDS, 16B per lane; LDS dest = wave-uniform base + lane*16
__device__ __forceinline__ void gld16(const void* g, void* l) {
    __builtin_amdgcn_global_load_lds(
        (const __attribute__((address_space(1))) void*)g,
        (__attribute__((address_space(3))) void*)l, 16, 0, 0);
}

// ---------------------------------------------------------------------------
// Fused prep: weight convert (blocks 0..1023) + GroupNorm partial stats
// (blocks 1024..1535, atomic accumulate into pre-zeroed stats).
// ---------------------------------------------------------------------------
__global__ __launch_bounds__(256) void prep_kernel(
    const float* __restrict__ qkv_w, const float* __restrict__ out_w,
    const float* __restrict__ x,
    unsigned short* __restrict__ wq_bf, unsigned short* __restrict__ wo_bf,
    float* __restrict__ stats)
{
    int bid = blockIdx.x;
    if (bid < 1024) {
        int i4 = bid * 256 + threadIdx.x;          // float4 index
        if (i4 < 196608) {                         // 1536*512/4
            float4 w = ((const float4*)qkv_w)[i4];
            int row = i4 >> 7;
            float sc = (row < 512) ? QSCALE : 1.0f;
            ushort4 o = { f2bf(w.x * sc), f2bf(w.y * sc), f2bf(w.z * sc), f2bf(w.w * sc) };
            *(ushort4*)&wq_bf[(size_t)i4 * 4] = o;
        } else {
            int j4 = i4 - 196608;
            float4 w = ((const float4*)out_w)[j4];
            ushort4 o = { f2bf(w.x), f2bf(w.y), f2bf(w.z), f2bf(w.w) };
            *(ushort4*)&wo_bf[(size_t)j4 * 4] = o;
        }
        return;
    }
    // ---- GN partial stats: 512 blocks, 4 partials per (b,g) ----
    const int CPG = CH / NGROUPS;              // 16
    int gb = bid - 1024;
    int bg = gb >> 2, part = gb & 3;
    int b = bg / NGROUPS, g = bg % NGROUPS;
    const size_t base = ((size_t)b * CH + (size_t)g * CPG) * NN
                      + (size_t)part * (CPG * NN / 4);
    const int total4 = CPG * NN / 16;          // 4096 float4 per part
    int tid = threadIdx.x;

    const float4* x4 = (const float4*)(x + base);
    float sum = 0.f, sumsq = 0.f;
    for (int i = tid; i < total4; i += 256) {
        float4 v = x4[i];
        sum   += v.x + v.y + v.z + v.w;
        sumsq += v.x*v.x + v.y*v.y + v.z*v.z + v.w*v.w;
    }
    for (int off = 32; off > 0; off >>= 1) {
        sum   += __shfl_down(sum, off);
        sumsq += __shfl_down(sumsq, off);
    }
    __shared__ float s_sum[4], s_sq[4];
    int wid = tid >> 6, lane = tid & 63;
    if (lane == 0) { s_sum[wid] = sum; s_sq[wid] = sumsq; }
    __syncthreads();
    if (tid == 0) {
        float ts = 0.f, tq = 0.f;
        for (int i = 0; i < 4; i++) { ts += s_sum[i]; tq += s_sq[i]; }
        atomicAdd(&stats[bg * 2 + 0], ts);
        atomicAdd(&stats[bg * 2 + 1], tq);
    }
}

// ---------------------------------------------------------------------------
// Transpose + inline GroupNorm apply (mean/rstd computed from raw sums):
//   xnT[b][n][c] = GN(x) bf16 ;  xT[b][n][c] = x bf16 (residual)
// ---------------------------------------------------------------------------
__global__ __launch_bounds__(256) void t1_kernel(
    const float* __restrict__ x, const float2* __restrict__ stats,
    const float* __restrict__ gamma, const float* __restrict__ beta,
    unsigned short* __restrict__ xnT, unsigned short* __restrict__ xT)
{
    __shared__ alignas(16) short Tn[64 * 80];
    __shared__ alignas(16) short Tr[64 * 80];
    int n0 = blockIdx.x * 64, c0 = blockIdx.y * 64, b = blockIdx.z;
    int tid = threadIdx.x;
    const float inv = 1.0f / 65536.0f;

    #pragma unroll
    for (int i = 0; i < 4; ++i) {
        int idx = tid + i * 256; int cl = idx >> 4, nq = idx & 15;
        int c = c0 + cl;
        float2 st = stats[b * NGROUPS + (c >> 4)];
        float mean = st.x * inv;
        float var  = st.y * inv - mean * mean;
        float rstd = rsqrtf(var + EPS);
        float gm = gamma[c], bt = beta[c];
        float4 f = *(const float4*)&x[((size_t)(b * CH + c)) * NN + n0 + nq * 4];
        float e0 = f.x, e1 = f.y, e2 = f.z, e3 = f.w;
        Tr[(nq * 4 + 0) * 80 + cl] = (short)f2bf(e0);
        Tr[(nq * 4 + 1) * 80 + cl] = (short)f2bf(e1);
        Tr[(nq * 4 + 2) * 80 + cl] = (short)f2bf(e2);
        Tr[(nq * 4 + 3) * 80 + cl] = (short)f2bf(e3);
        Tn[(nq * 4 + 0) * 80 + cl] = (short)f2bf((e0 - mean) * rstd * gm + bt);
        Tn[(nq * 4 + 1) * 80 + cl] = (short)f2bf((e1 - mean) * rstd * gm + bt);
        Tn[(nq * 4 + 2) * 80 + cl] = (short)f2bf((e2 - mean) * rstd * gm + bt);
        Tn[(nq * 4 + 3) * 80 + cl] = (short)f2bf((e3 - mean) * rstd * gm + bt);
    }
    __syncthreads();
    #pragma unroll
    for (int i = 0; i < 2; ++i) {
        int idx = tid + i * 256; int n = idx >> 3, ck = idx & 7;
        size_t gidx = ((size_t)(b * NN + n0 + n)) * CH + c0 + ck * 8;
        *(uint4*)&xnT[gidx] = *(uint4*)&Tn[n * 80 + ck * 8];
        *(uint4*)&xT[gidx]  = *(uint4*)&Tr[n * 80 + ck * 8];
    }
}

// ---------------------------------------------------------------------------
// MFMA GEMM: out[b][m][n] = A[m][:]·Bt[b][n][:] + bias
// Main loop: global_load_lds double-buffered staging, linear LDS dest
// [128][64] bf16, pre-swizzled global source L = s^(r&7), XOR-swizzled
// ds_read_b128, ONE barrier/K-step.  (Round-7: this cut gemm0 ~2x.)
// ---------------------------------------------------------------------------
template<int MODE>
__global__ __launch_bounds__(256) void gemm_kernel(
    const unsigned short* __restrict__ A,    // [M][512] bf16
    const unsigned short* __restrict__ Bt,   // [B][4096][512] bf16
    const float* __restrict__ bias,          // [M]
    unsigned short* __restrict__ qT, unsigned short* __restrict__ kT,
    unsigned short* __restrict__ v, float* __restrict__ out)
{
    __shared__ alignas(16) short smem[2][2][128 * 64];   // [buf][A|B], 64KB
    short* Es = (short*)smem;                            // MODE0 epi: 128*132 shorts
    float* Ef = (float*)smem;                            // MODE1 epi: 128*66 floats

    constexpr int GY = (MODE == 0) ? 12 : 4;
    int lin = blockIdx.x + 32 * (blockIdx.y + GY * blockIdx.z);
    constexpr int CPX = 32 * GY * 4 / 8;
    int wg = (lin & 7) * CPX + (lin >> 3);
    const int n0 = (wg % 32) * 128;
    const int m0 = ((wg / 32) % GY) * 128;
    const int b  = wg / (32 * GY);

    const int tid = threadIdx.x;
    const int wid = tid >> 6, l = tid & 63, lr = l & 15, lk = l >> 4;
    const int wm = (wid & 1) * 64, wn = (wid >> 1) * 64;
    const unsigned short* Bb = Bt + (size_t)b * NN * CH;

    // staging: 16KB/tensor = 16 x 1KB chunks, 4 chunks/wave per tensor.
    int rr[4], LL[4], ch[4];
    #pragma unroll
    for (int i = 0; i < 4; ++i) {
        ch[i] = (wid * 4 + i) * 1024;
        int li = ch[i] + l * 16;
        int r = li >> 7, s = (li >> 4) & 7;
        rr[i] = r; LL[i] = s ^ (r & 7);
    }

    #define GSTAGE(buf, k0) do {                                                   \
        _Pragma("unroll")                                                          \
        for (int i = 0; i < 4; ++i) {                                              \
            gld16(&A [((size_t)(m0 + rr[i])) * CH + (k0) + LL[i] * 8],             \
                  (char*)&smem[buf][0][0] + ch[i]);                                \
            gld16(&Bb[((size_t)(n0 + rr[i])) * CH + (k0) + LL[i] * 8],             \
                  (char*)&smem[buf][1][0] + ch[i]);                                \
        }                                                                          \
    } while (0)

    f32x4 acc[4][4];
    #pragma unroll
    for (int i = 0; i < 4; ++i)
        #pragma unroll
        for (int j = 0; j < 4; ++j) acc[i][j] = (f32x4){0.f, 0.f, 0.f, 0.f};

    GSTAGE(0, 0);
    __syncthreads();   // drains vmcnt -> tile 0 staged

    int cur = 0;
    for (int ks = 0; ks < 8; ++ks) {
        if (ks < 7) GSTAGE(cur ^ 1, (ks + 1) * 64);   // in flight during compute
        const char* As = (const char*)&smem[cur][0][0];
        const char* Bs = (const char*)&smem[cur][1][0];
        #pragma unroll
        for (int kh = 0; kh < 2; ++kh) {
            const int sw = ((kh * 4 + lk) ^ (lr & 7)) << 4;
            bf16x8 af[4], bfr[4];
            #pragma unroll
            for (int t = 0; t < 4; ++t) {
                af[t]  = *(const bf16x8*)(As + (wm + t * 16 + lr) * 128 + sw);
                bfr[t] = *(const bf16x8*)(Bs + (wn + t * 16 + lr) * 128 + sw);
            }
            #pragma unroll
            for (int mt = 0; mt < 4; ++mt)
                #pragma unroll
                for (int nt = 0; nt < 4; ++nt)
                    acc[mt][nt] = __builtin_amdgcn_mfma_f32_16x16x32_bf16(
                        af[mt], bfr[nt], acc[mt][nt], 0, 0, 0);
        }
        __syncthreads();   // drains vmcnt (next tile) + guards buffer reuse
        cur ^= 1;
    }
    #undef GSTAGE

    if (MODE == 0) {
        const bool isV = (m0 >= 1024);
        #pragma unroll
        for (int mt = 0; mt < 4; ++mt) {
            int mbase = m0 + wm + mt * 16 + lk * 4;
            int ml = wm + mt * 16 + lk * 4;
            float bsc = (m0 < 512) ? QSCALE : 1.0f;
            #pragma unroll
            for (int nt = 0; nt < 4; ++nt) {
                int nl = wn + nt * 16 + lr;
                f32x4 vv = acc[mt][nt];
                if (!isV) {
                    ushort4 o;
                    o.x = f2bf(vv[0] + bias[mbase + 0] * bsc);
                    o.y = f2bf(vv[1] + bias[mbase + 1] * bsc);
                    o.z = f2bf(vv[2] + bias[mbase + 2] * bsc);
                    o.w = f2bf(vv[3] + bias[mbase + 3] * bsc);
                    *(ushort4*)&Es[nl * 132 + ml] = o;
                } else {
                    #pragma unroll
                    for (int j = 0; j < 4; ++j)
                        Es[(ml + j) * 132 + nl] = (short)f2bf(vv[j] + bias[mbase + j]);
                }
            }
        }
        __syncthreads();
        int r16 = tid >> 4, c16 = tid & 15;
        if (!isV) {
            unsigned short* dst;
            if (m0 < 512) dst = qT + (((size_t)(b * 4 + (m0 >> 7))) * NN + n0) * 128;
            else          dst = kT + (((size_t)(b * 4 + ((m0 - 512) >> 7))) * NN + n0) * 128;
            #pragma unroll
            for (int p = 0; p < 8; ++p) {
                int nl = p * 16 + r16;
                uint4 w = *(const uint4*)&Es[nl * 132 + c16 * 8];
                *(uint4*)&dst[(size_t)nl * 128 + c16 * 8] = w;
            }
        } else {
            unsigned short* dst = v + ((size_t)(b * 512 + (m0 - 1024)) * NN) + n0;
            #pragma unroll
            for (int p = 0; p < 8; ++p) {
                int ml = p * 16 + r16;
                uint4 w = *(const uint4*)&Es[ml * 132 + c16 * 8];
                *(uint4*)&dst[(size_t)ml * NN + c16 * 8] = w;
            }
        }
    } else {
        // fp32 out: LDS transpose in 2 n-halves -> full 256B-row float4 stores
        for (int half = 0; half < 2; ++half) {
            __syncthreads();
            if ((wn >> 6) == half) {
                #pragma unroll
                for (int mt = 0; mt < 4; ++mt) {
                    int ml = wm + mt * 16 + lk * 4;
                    int mbase = m0 + ml;
                    #pragma unroll
                    for (int nt = 0; nt < 4; ++nt) {
                        int nl = nt * 16 + lr;          // 0..63 within half
                        f32x4 vv = acc[mt][nt];
                        #pragma unroll
                        for (int j = 0; j < 4; ++j)
                            Ef[(ml + j) * 66 + nl] = vv[j] + bias[mbase + j];
                    }
                }
            }
            __syncthreads();
            #pragma unroll
            for (int i = 0; i < 8; ++i) {
                int idx = tid + i * 256;                // 0..2047 float4s
                int r = idx >> 4, c4 = idx & 15;
                float4 w = *(const float4*)&Ef[r * 66 + c4 * 4];
                *(float4*)&out[((size_t)(b * CH + m0 + r)) * NN + n0 + half * 64 + c4 * 4] = w;
            }
        }
    }
}

// ---------------------------------------------------------------------------
// Flash attention, 32x32 MFMA + in-register P (T12).  KVBLK=64, 4 waves x
// 32 q rows, double-buffered K/V via global_load_lds (pre-swizzled source,
// linear LDS dest, swizzled reads), 4-bit XOR swizzle (2-way, free).
// PROVEN config: 171us, 0 bank conflicts, 800 TF effective (~89% of the
// best-known plain-HIP attn on MI355X).
// Structural attacks that all FAILED (keep for the record):
//   - KVBLK=32 + (256,4): VGPR spill, 2.2x regression (round 4)
//   - KV-split x2 + merge: occupancy unchanged, +32us overhead (round 6)
//   - ones-MFMA denominator: pipe-cosmetic, wall unchanged (round 8)
//   - 2-wave single-buffered blocks: staging serialized, +24us (round 9)
// ---------------------------------------------------------------------------
__global__ __launch_bounds__(256, 2) void attn_kernel(
    const unsigned short* __restrict__ qT,  // [BH][N][128] (pre-scaled by SCALE*log2e)
    const unsigned short* __restrict__ kT,  // [BH][N][128]
    const unsigned short* __restrict__ vg,  // [BH*128][N]
    const unsigned short* __restrict__ xT,  // [B][N][512] residual bf16
    unsigned short* __restrict__ aoT)       // [B][N][512]
{
    __shared__ alignas(16) short Ks[2][64 * 128];   // 16KB/buf: 64 rows x 256B
    __shared__ alignas(16) short Vs[2][64 * 128];   // 16KB/buf: 64 rows x 256B (d,d+64 pairs)

    // bijective XCD swizzle: 512 wgs, 8 XCDs -> 64 consecutive wgs per XCD
    int lin_id = blockIdx.x + 32 * (blockIdx.y + 4 * blockIdx.z);
    int wg = (lin_id & 7) * 64 + (lin_id >> 3);
    const int n0 = (wg & 31) * 128;
    const int h  = (wg >> 5) & 3;
    const int b  = wg >> 7;

    const int bh = b * 4 + h;
    const int tid = threadIdx.x, wid = tid >> 6, l = tid & 63;
    const int lq = l & 31, hi = l >> 5;
    const int wq0 = wid * 32;
    const int swz4 = (l & 15) << 4;             // read-side XOR, bits 4-7
    const unsigned short* Qg = qT + (size_t)bh * NN * 128;
    const unsigned short* Kg = kT + (size_t)bh * NN * 128;
    const unsigned short* Vg = vg + (size_t)bh * 128 * NN;

    // staging geometry: 16 x 1KB chunks per tile per tensor, 4 chunks/wave.
    int kr[4], kc[4], vdd[4], vcc[4], ch[4];
    #pragma unroll
    for (int i = 0; i < 4; ++i) {
        ch[i] = (wid * 4 + i) * 1024;
        int li = ch[i] + l * 16;
        int r = li >> 8, s = (li >> 4) & 15;
        int L = s ^ (r & 15);
        kr[i] = r; kc[i] = L;
        vdd[i] = r + 64 * (L >> 3);
        vcc[i] = L & 7;
    }

    #define STAGE(buf, m0k) do {                                                   \
        _Pragma("unroll")                                                          \
        for (int i = 0; i < 4; ++i) {                                              \
            gld16(&Kg[(size_t)((m0k) + kr[i]) * 128 + kc[i] * 8],                  \
                  (char*)&Ks[buf][0] + ch[i]);                                     \
            gld16(&Vg[(size_t)vdd[i] * NN + (m0k) + vcc[i] * 8],                   \
                  (char*)&Vs[buf][0] + ch[i]);                                     \
        }                                                                          \
    } while (0)

    STAGE(0, 0);

    // ---- Q -> registers (overlaps staging latency) ----
    bf16x8 qr[8];
    #pragma unroll
    for (int dk = 0; dk < 8; ++dk)
        qr[dk] = *(const bf16x8*)&Qg[((size_t)(n0 + wq0 + lq)) * 128 + dk * 16 + hi * 8];

    f32x16 ov[4];
    #pragma unroll
    for (int dt = 0; dt < 4; ++dt)
        #pragma unroll
        for (int r = 0; r < 16; ++r) ov[dt][r] = 0.f;
    float mrun = -1e30f, lrun = 0.f;

    __syncthreads();   // drains vmcnt -> tile 0 staged

    int cur = 0;
    for (int t = 0; t < 64; ++t) {
        if (t < 63) STAGE(cur ^ 1, (t + 1) * 64);   // in flight during compute

        const char* Kc = (const char*)&Ks[cur][0];
        const char* Vc = (const char*)&Vs[cur][0];

        // ---- QK^T (32x32x16): col = q = lq, row k-local = (reg&3)+8*(reg>>2)+4*hi
        f32x16 s0, s1;
        #pragma unroll
        for (int r = 0; r < 16; ++r) { s0[r] = 0.f; s1[r] = 0.f; }
        __builtin_amdgcn_s_setprio(1);
        #pragma unroll
        for (int dk = 0; dk < 8; ++dk) {
            bf16x8 k0 = *(const bf16x8*)(Kc + (lq)      * 256 + ((dk * 32 + hi * 16) ^ swz4));
            bf16x8 k1 = *(const bf16x8*)(Kc + (32 + lq) * 256 + ((dk * 32 + hi * 16) ^ swz4));
            s0 = __builtin_amdgcn_mfma_f32_32x32x16_bf16(k0, qr[dk], s0, 0, 0, 0);
            s1 = __builtin_amdgcn_mfma_f32_32x32x16_bf16(k1, qr[dk], s1, 0, 0, 0);
        }
        __builtin_amdgcn_s_setprio(0);

        // ---- in-register online softmax (log2 domain) ----
        float m8[8];
        #pragma unroll
        for (int r = 0; r < 8; ++r)
            m8[r] = fmaxf(fmaxf(s0[r], s0[r + 8]), fmaxf(s1[r], s1[r + 8]));
        float t0 = fmaxf(fmaxf(m8[0], m8[1]), m8[2]);
        float t1_ = fmaxf(fmaxf(m8[3], m8[4]), m8[5]);
        float t2 = fmaxf(fmaxf(m8[6], m8[7]), t0);
        float pm = fmaxf(t1_, t2);
        pm = fmaxf(pm, __shfl_xor(pm, 32));

        int defer = (pm - mrun) <= THR;
        if (!__all(defer)) {
            float mnew = fmaxf(mrun, pm);
            float corr = fexp2(mrun - mnew);
            lrun *= corr; mrun = mnew;
            #pragma unroll
            for (int dt = 0; dt < 4; ++dt)
                #pragma unroll
                for (int r = 0; r < 16; ++r) ov[dt][r] *= corr;
        }
        float ps = 0.f;
        #pragma unroll
        for (int r = 0; r < 16; ++r) { float e = fexp2(s0[r] - mrun); s0[r] = e; ps += e; }
        #pragma unroll
        for (int r = 0; r < 16; ++r) { float e = fexp2(s1[r] - mrun); s1[r] = e; ps += e; }
        ps += __shfl_xor(ps, 32);
        lrun += ps;

        // ---- P -> bf16 + in-register redistribution (T12) ----
        unsigned int u0[8], u1[8];
        #pragma unroll
        for (int m = 0; m < 8; ++m) {
            u0[m] = cvtpk(s0[2 * m], s0[2 * m + 1]);
            u1[m] = cvtpk(s1[2 * m], s1[2 * m + 1]);
        }
        bf16x8 pf[4];
        #pragma unroll
        for (int kt = 0; kt < 2; ++kt)
            #pragma unroll
            for (int hh = 0; hh < 2; ++hh) {
                const unsigned int* u = kt ? u1 : u0;
                unsigned int w0 = u[4*hh + 0], w2 = u[4*hh + 2];
                unsigned int w1 = u[4*hh + 1], w3 = u[4*hh + 3];
                asm("v_permlane32_swap_b32 %0, %1" : "+v"(w0), "+v"(w2));
                asm("v_permlane32_swap_b32 %0, %1" : "+v"(w1), "+v"(w3));
                unsigned int w[4] = { w0, w1, w2, w3 };
                bf16x8 p; __builtin_memcpy(&p, w, 16);
                pf[kt * 2 + hh] = p;
            }

        // ---- PV (32x32x16): ov[dt] += V^T-tile · P ----
        __builtin_amdgcn_s_setprio(1);
        #pragma unroll
        for (int dt = 0; dt < 4; ++dt)
            #pragma unroll
            for (int kt2 = 0; kt2 < 4; ++kt2) {
                bf16x8 vf = *(const bf16x8*)(Vc + ((dt & 1) * 32 + lq) * 256 +
                                             ((((dt >> 1) * 8 + kt2 * 2 + hi) << 4) ^ swz4));
                ov[dt] = __builtin_amdgcn_mfma_f32_32x32x16_bf16(vf, pf[kt2], ov[dt], 0, 0, 0);
            }
        __builtin_amdgcn_s_setprio(0);

        __syncthreads();   // drains vmcnt (t+1 staged) + guards buffer reuse
        cur ^= 1;
    }
    #undef STAGE

    // ---- epilogue: normalize, add residual, store aoT ----
    float linv = 1.0f / lrun;
    const int n = n0 + wq0 + lq;
    #pragma unroll
    for (int dt = 0; dt < 4; ++dt)
        #pragma unroll
        for (int m = 0; m < 4; ++m) {
            int d = dt * 32 + m * 8 + hi * 4;
            size_t gidx = ((size_t)(b * NN + n)) * CH + h * 128 + d;
            unsigned short xv[4];
            *(ushort4*)xv = *(const ushort4*)&xT[gidx];
            unsigned int w0 = cvtpk(ov[dt][4*m + 0] * linv + bf2f(xv[0]),
                                    ov[dt][4*m + 1] * linv + bf2f(xv[1]));
            unsigned int w1 = cvtpk(ov[dt][4*m + 2] * linv + bf2f(xv[2]),
                                    ov[dt][4*m + 3] * linv + bf2f(xv[3]));
            unsigned long long wv = (unsigned long long)w0 |
                                    ((unsigned long long)w1 << 32);
            *(unsigned long long*)&aoT[gidx] = wv;
        }
}

// ---------------------------------------------------------------------------
extern "C" void kernel_launch(void* const* d_in, const int* in_sizes, int n_in,
                              void* d_out, int out_size, void* d_ws, size_t ws_size,
                              hipStream_t stream) {
    const float* x      = (const float*)d_in[0];
    const float* gamma  = (const float*)d_in[1];
    const float* beta   = (const float*)d_in[2];
    const float* qkv_w  = (const float*)d_in[3];
    const float* qkv_b  = (const float*)d_in[4];
    const float* out_w  = (const float*)d_in[5];
    const float* out_b  = (const float*)d_in[6];
    float* out = (float*)d_out;

    char* ws = (char*)d_ws;
    const size_t SZ = (size_t)BB * CH * NN * 2;     // 16 MB per bf16 tensor
    unsigned short* xnT   = (unsigned short*)(ws);
    unsigned short* xT    = (unsigned short*)(ws + SZ);
    unsigned short* qT    = (unsigned short*)(ws + 2 * SZ);
    unsigned short* kT    = (unsigned short*)(ws + 3 * SZ);
    unsigned short* vbuf  = (unsigned short*)(ws + 4 * SZ);
    unsigned short* aoT   = (unsigned short*)(ws + 5 * SZ);
    unsigned short* wq_bf = (unsigned short*)(ws + 6 * SZ);
    unsigned short* wo_bf = (unsigned short*)(ws + 6 * SZ + (size_t)1536 * 512 * 2);
    float* stats = (float*)(ws + 6 * SZ + (size_t)2048 * 512 * 2);

    hipMemsetAsync(stats, 0, 256 * sizeof(float), stream);
    prep_kernel<<<dim3(1536), 256, 0, stream>>>(qkv_w, out_w, x, wq_bf, wo_bf, stats);
    t1_kernel<<<dim3(NN / 64, CH / 64, BB), 256, 0, stream>>>(
        x, (const float2*)stats, gamma, beta, xnT, xT);
    gemm_kernel<0><<<dim3(NN / 128, 1536 / 128, BB), 256, 0, stream>>>(
        wq_bf, xnT, qkv_b, qT, kT, vbuf, nullptr);
    attn_kernel<<<dim3(NN / 128, NHEADS, BB), 256, 0, stream>>>(qT, kT, vbuf, xT, aoT);
    gemm_kernel<1><<<dim3(NN / 128, CH / 128, BB), 256, 0, stream>>>(
        wo_bf, aoT, out_b, nullptr, nullptr, nullptr, out);
}

// Round 11
// 250.816 us; speedup vs baseline: 1.1305x; 1.0335x over previous
//
#include <hip/hip_runtime.h>
#include <math.h>

constexpr int BB = 4, CH = 512, NN = 4096, NHEADS = 4, NGROUPS = 32, HCH = 128;
constexpr float EPS = 1e-5f;
constexpr float SCALE = 0.08838834764831845f;  // 128^-0.5
constexpr float LOG2E = 1.4426950408889634f;
constexpr float QSCALE = SCALE * LOG2E;        // fold exp->exp2 domain into Q
constexpr float THR = 11.541560327111707f;     // 8 * log2(e)

typedef short bf16x8 __attribute__((ext_vector_type(8)));
typedef float f32x4 __attribute__((ext_vector_type(4)));
typedef float f32x16 __attribute__((ext_vector_type(16)));

__device__ __forceinline__ float bf2f(unsigned short u) {
    unsigned int x = ((unsigned int)u) << 16;
    float f; __builtin_memcpy(&f, &x, 4); return f;
}
__device__ __forceinline__ unsigned short f2bf(float f) {
    unsigned int x; __builtin_memcpy(&x, &f, 4);
    x += 0x7fff + ((x >> 16) & 1);          // RNE
    return (unsigned short)(x >> 16);
}
// RNE pack of 2 f32 -> 2 bf16 in one u32 (no builtin on gfx950; m240)
__device__ __forceinline__ unsigned int cvtpk(float lo, float hi) {
    unsigned int r;
    asm("v_cvt_pk_bf16_f32 %0, %1, %2" : "=v"(r) : "v"(lo), "v"(hi));
    return r;
}
// raw 2^x (exp2f without fast-math lowers to a multi-instr ocml fixup path)
__device__ __forceinline__ float fexp2(float x) {
    float r; asm("v_exp_f32 %0, %1" : "=v"(r) : "v"(x)); return r;
}

// async global->LDS, 16B per lane; LDS dest = wave-uniform base + lane*16
__device__ __forceinline__ void gld16(const void* g, void* l) {
    __builtin_amdgcn_global_load_lds(
        (const __attribute__((address_space(1))) void*)g,
        (__attribute__((address_space(3))) void*)l, 16, 0, 0);
}

// ---------------------------------------------------------------------------
// Fused prep: weight convert (blocks 0..1023) + GroupNorm partial stats
// (blocks 1024..1535, atomic accumulate into pre-zeroed stats).
// ---------------------------------------------------------------------------
__global__ __launch_bounds__(256) void prep_kernel(
    const float* __restrict__ qkv_w, const float* __restrict__ out_w,
    const float* __restrict__ x,
    unsigned short* __restrict__ wq_bf, unsigned short* __restrict__ wo_bf,
    float* __restrict__ stats)
{
    int bid = blockIdx.x;
    if (bid < 1024) {
        int i4 = bid * 256 + threadIdx.x;          // float4 index
        if (i4 < 196608) {                         // 1536*512/4
            float4 w = ((const float4*)qkv_w)[i4];
            int row = i4 >> 7;
            float sc = (row < 512) ? QSCALE : 1.0f;
            ushort4 o = { f2bf(w.x * sc), f2bf(w.y * sc), f2bf(w.z * sc), f2bf(w.w * sc) };
            *(ushort4*)&wq_bf[(size_t)i4 * 4] = o;
        } else {
            int j4 = i4 - 196608;
            float4 w = ((const float4*)out_w)[j4];
            ushort4 o = { f2bf(w.x), f2bf(w.y), f2bf(w.z), f2bf(w.w) };
            *(ushort4*)&wo_bf[(size_t)j4 * 4] = o;
        }
        return;
    }
    // ---- GN partial stats: 512 blocks, 4 partials per (b,g) ----
    const int CPG = CH / NGROUPS;              // 16
    int gb = bid - 1024;
    int bg = gb >> 2, part = gb & 3;
    int b = bg / NGROUPS, g = bg % NGROUPS;
    const size_t base = ((size_t)b * CH + (size_t)g * CPG) * NN
                      + (size_t)part * (CPG * NN / 4);
    const int total4 = CPG * NN / 16;          // 4096 float4 per part
    int tid = threadIdx.x;

    const float4* x4 = (const float4*)(x + base);
    float sum = 0.f, sumsq = 0.f;
    for (int i = tid; i < total4; i += 256) {
        float4 v = x4[i];
        sum   += v.x + v.y + v.z + v.w;
        sumsq += v.x*v.x + v.y*v.y + v.z*v.z + v.w*v.w;
    }
    for (int off = 32; off > 0; off >>= 1) {
        sum   += __shfl_down(sum, off);
        sumsq += __shfl_down(sumsq, off);
    }
    __shared__ float s_sum[4], s_sq[4];
    int wid = tid >> 6, lane = tid & 63;
    if (lane == 0) { s_sum[wid] = sum; s_sq[wid] = sumsq; }
    __syncthreads();
    if (tid == 0) {
        float ts = 0.f, tq = 0.f;
        for (int i = 0; i < 4; i++) { ts += s_sum[i]; tq += s_sq[i]; }
        atomicAdd(&stats[bg * 2 + 0], ts);
        atomicAdd(&stats[bg * 2 + 1], tq);
    }
}

// ---------------------------------------------------------------------------
// Transpose + inline GroupNorm apply (mean/rstd computed from raw sums):
//   xnT[b][n][c] = GN(x) bf16 ;  xT[b][n][c] = x bf16 (residual)
// LDS columns XOR-swizzled at 8-short granularity keyed by (row>>2)&7:
// the unswizzled scalar transpose writes were a 32-way bank conflict
// (row stride 80 shorts = 40 dwords; 4-row step = 160 dwords = 0 mod 32,
// so all 16 nq lanes hit bank 8j + cl>>1).  Swizzle -> 4-way (1.58x, near
// free); 16B reads un-XOR with the same key (mult of 8 keeps alignment).
// ---------------------------------------------------------------------------
__global__ __launch_bounds__(256) void t1_kernel(
    const float* __restrict__ x, const float2* __restrict__ stats,
    const float* __restrict__ gamma, const float* __restrict__ beta,
    unsigned short* __restrict__ xnT, unsigned short* __restrict__ xT)
{
    __shared__ alignas(16) short Tn[64 * 80];
    __shared__ alignas(16) short Tr[64 * 80];
    int n0 = blockIdx.x * 64, c0 = blockIdx.y * 64, b = blockIdx.z;
    int tid = threadIdx.x;
    const float inv = 1.0f / 65536.0f;

    #pragma unroll
    for (int i = 0; i < 4; ++i) {
        int idx = tid + i * 256; int cl = idx >> 4, nq = idx & 15;
        int c = c0 + cl;
        float2 st = stats[b * NGROUPS + (c >> 4)];
        float mean = st.x * inv;
        float var  = st.y * inv - mean * mean;
        float rstd = rsqrtf(var + EPS);
        float gm = gamma[c], bt = beta[c];
        float4 f = *(const float4*)&x[((size_t)(b * CH + c)) * NN + n0 + nq * 4];
        float e0 = f.x, e1 = f.y, e2 = f.z, e3 = f.w;
        int cs = cl ^ ((nq & 7) << 3);          // row = nq*4+j -> key (row>>2)&7 = nq&7
        Tr[(nq * 4 + 0) * 80 + cs] = (short)f2bf(e0);
        Tr[(nq * 4 + 1) * 80 + cs] = (short)f2bf(e1);
        Tr[(nq * 4 + 2) * 80 + cs] = (short)f2bf(e2);
        Tr[(nq * 4 + 3) * 80 + cs] = (short)f2bf(e3);
        Tn[(nq * 4 + 0) * 80 + cs] = (short)f2bf((e0 - mean) * rstd * gm + bt);
        Tn[(nq * 4 + 1) * 80 + cs] = (short)f2bf((e1 - mean) * rstd * gm + bt);
        Tn[(nq * 4 + 2) * 80 + cs] = (short)f2bf((e2 - mean) * rstd * gm + bt);
        Tn[(nq * 4 + 3) * 80 + cs] = (short)f2bf((e3 - mean) * rstd * gm + bt);
    }
    __syncthreads();
    #pragma unroll
    for (int i = 0; i < 2; ++i) {
        int idx = tid + i * 256; int n = idx >> 3, ck = idx & 7;
        int cs8 = (ck * 8) ^ (((n >> 2) & 7) << 3);   // same involution, 8-aligned
        size_t gidx = ((size_t)(b * NN + n0 + n)) * CH + c0 + ck * 8;
        *(uint4*)&xnT[gidx] = *(uint4*)&Tn[n * 80 + cs8];
        *(uint4*)&xT[gidx]  = *(uint4*)&Tr[n * 80 + cs8];
    }
}

// ---------------------------------------------------------------------------
// MFMA GEMM: out[b][m][n] = A[m][:]·Bt[b][n][:] + bias
// Main loop: global_load_lds double-buffered staging, linear LDS dest
// [128][64] bf16, pre-swizzled global source L = s^(r&7), XOR-swizzled
// ds_read_b128, ONE barrier/K-step.  (Round-7: this cut gemm0 ~2x.)
// ---------------------------------------------------------------------------
template<int MODE>
__global__ __launch_bounds__(256) void gemm_kernel(
    const unsigned short* __restrict__ A,    // [M][512] bf16
    const unsigned short* __restrict__ Bt,   // [B][4096][512] bf16
    const float* __restrict__ bias,          // [M]
    unsigned short* __restrict__ qT, unsigned short* __restrict__ kT,
    unsigned short* __restrict__ v, float* __restrict__ out)
{
    __shared__ alignas(16) short smem[2][2][128 * 64];   // [buf][A|B], 64KB
    short* Es = (short*)smem;                            // MODE0 epi: 128*132 shorts
    float* Ef = (float*)smem;                            // MODE1 epi: 128*66 floats

    constexpr int GY = (MODE == 0) ? 12 : 4;
    int lin = blockIdx.x + 32 * (blockIdx.y + GY * blockIdx.z);
    constexpr int CPX = 32 * GY * 4 / 8;
    int wg = (lin & 7) * CPX + (lin >> 3);
    const int n0 = (wg % 32) * 128;
    const int m0 = ((wg / 32) % GY) * 128;
    const int b  = wg / (32 * GY);

    const int tid = threadIdx.x;
    const int wid = tid >> 6, l = tid & 63, lr = l & 15, lk = l >> 4;
    const int wm = (wid & 1) * 64, wn = (wid >> 1) * 64;
    const unsigned short* Bb = Bt + (size_t)b * NN * CH;

    // staging: 16KB/tensor = 16 x 1KB chunks, 4 chunks/wave per tensor.
    int rr[4], LL[4], ch[4];
    #pragma unroll
    for (int i = 0; i < 4; ++i) {
        ch[i] = (wid * 4 + i) * 1024;
        int li = ch[i] + l * 16;
        int r = li >> 7, s = (li >> 4) & 7;
        rr[i] = r; LL[i] = s ^ (r & 7);
    }

    #define GSTAGE(buf, k0) do {                                                   \
        _Pragma("unroll")                                                          \
        for (int i = 0; i < 4; ++i) {                                              \
            gld16(&A [((size_t)(m0 + rr[i])) * CH + (k0) + LL[i] * 8],             \
                  (char*)&smem[buf][0][0] + ch[i]);                                \
            gld16(&Bb[((size_t)(n0 + rr[i])) * CH + (k0) + LL[i] * 8],             \
                  (char*)&smem[buf][1][0] + ch[i]);                                \
        }                                                                          \
    } while (0)

    f32x4 acc[4][4];
    #pragma unroll
    for (int i = 0; i < 4; ++i)
        #pragma unroll
        for (int j = 0; j < 4; ++j) acc[i][j] = (f32x4){0.f, 0.f, 0.f, 0.f};

    GSTAGE(0, 0);
    __syncthreads();   // drains vmcnt -> tile 0 staged

    int cur = 0;
    for (int ks = 0; ks < 8; ++ks) {
        if (ks < 7) GSTAGE(cur ^ 1, (ks + 1) * 64);   // in flight during compute
        const char* As = (const char*)&smem[cur][0][0];
        const char* Bs = (const char*)&smem[cur][1][0];
        #pragma unroll
        for (int kh = 0; kh < 2; ++kh) {
            const int sw = ((kh * 4 + lk) ^ (lr & 7)) << 4;
            bf16x8 af[4], bfr[4];
            #pragma unroll
            for (int t = 0; t < 4; ++t) {
                af[t]  = *(const bf16x8*)(As + (wm + t * 16 + lr) * 128 + sw);
                bfr[t] = *(const bf16x8*)(Bs + (wn + t * 16 + lr) * 128 + sw);
            }
            #pragma unroll
            for (int mt = 0; mt < 4; ++mt)
                #pragma unroll
                for (int nt = 0; nt < 4; ++nt)
                    acc[mt][nt] = __builtin_amdgcn_mfma_f32_16x16x32_bf16(
                        af[mt], bfr[nt], acc[mt][nt], 0, 0, 0);
        }
        __syncthreads();   // drains vmcnt (next tile) + guards buffer reuse
        cur ^= 1;
    }
    #undef GSTAGE

    if (MODE == 0) {
        const bool isV = (m0 >= 1024);
        #pragma unroll
        for (int mt = 0; mt < 4; ++mt) {
            int mbase = m0 + wm + mt * 16 + lk * 4;
            int ml = wm + mt * 16 + lk * 4;
            float bsc = (m0 < 512) ? QSCALE : 1.0f;
            #pragma unroll
            for (int nt = 0; nt < 4; ++nt) {
                int nl = wn + nt * 16 + lr;
                f32x4 vv = acc[mt][nt];
                if (!isV) {
                    ushort4 o;
                    o.x = f2bf(vv[0] + bias[mbase + 0] * bsc);
                    o.y = f2bf(vv[1] + bias[mbase + 1] * bsc);
                    o.z = f2bf(vv[2] + bias[mbase + 2] * bsc);
                    o.w = f2bf(vv[3] + bias[mbase + 3] * bsc);
                    *(ushort4*)&Es[nl * 132 + ml] = o;
                } else {
                    #pragma unroll
                    for (int j = 0; j < 4; ++j)
                        Es[(ml + j) * 132 + nl] = (short)f2bf(vv[j] + bias[mbase + j]);
                }
            }
        }
        __syncthreads();
        int r16 = tid >> 4, c16 = tid & 15;
        if (!isV) {
            unsigned short* dst;
            if (m0 < 512) dst = qT + (((size_t)(b * 4 + (m0 >> 7))) * NN + n0) * 128;
            else          dst = kT + (((size_t)(b * 4 + ((m0 - 512) >> 7))) * NN + n0) * 128;
            #pragma unroll
            for (int p = 0; p < 8; ++p) {
                int nl = p * 16 + r16;
                uint4 w = *(const uint4*)&Es[nl * 132 + c16 * 8];
                *(uint4*)&dst[(size_t)nl * 128 + c16 * 8] = w;
            }
        } else {
            unsigned short* dst = v + ((size_t)(b * 512 + (m0 - 1024)) * NN) + n0;
            #pragma unroll
            for (int p = 0; p < 8; ++p) {
                int ml = p * 16 + r16;
                uint4 w = *(const uint4*)&Es[ml * 132 + c16 * 8];
                *(uint4*)&dst[(size_t)ml * NN + c16 * 8] = w;
            }
        }
    } else {
        // fp32 out: LDS transpose in 2 n-halves -> full 256B-row float4 stores
        for (int half = 0; half < 2; ++half) {
            __syncthreads();
            if ((wn >> 6) == half) {
                #pragma unroll
                for (int mt = 0; mt < 4; ++mt) {
                    int ml = wm + mt * 16 + lk * 4;
                    int mbase = m0 + ml;
                    #pragma unroll
                    for (int nt = 0; nt < 4; ++nt) {
                        int nl = nt * 16 + lr;          // 0..63 within half
                        f32x4 vv = acc[mt][nt];
                        #pragma unroll
                        for (int j = 0; j < 4; ++j)
                            Ef[(ml + j) * 66 + nl] = vv[j] + bias[mbase + j];
                    }
                }
            }
            __syncthreads();
            #pragma unroll
            for (int i = 0; i < 8; ++i) {
                int idx = tid + i * 256;                // 0..2047 float4s
                int r = idx >> 4, c4 = idx & 15;
                float4 w = *(const float4*)&Ef[r * 66 + c4 * 4];
                *(float4*)&out[((size_t)(b * CH + m0 + r)) * NN + n0 + half * 64 + c4 * 4] = w;
            }
        }
    }
}

// ---------------------------------------------------------------------------
// Flash attention, 32x32 MFMA + in-register P (T12).  KVBLK=64, 4 waves x
// 32 q rows, double-buffered K/V via global_load_lds (pre-swizzled source,
// linear LDS dest, swizzled reads), 4-bit XOR swizzle (2-way, free).
// PROVEN config: 171us, 0 bank conflicts, 800 TF effective (~89% of the
// best-known plain-HIP attn on MI355X).
// Structural attacks that all FAILED (keep for the record):
//   - KVBLK=32 + (256,4): VGPR spill, 2.2x regression (round 4)
//   - KV-split x2 + merge: occupancy unchanged, +32us overhead (round 6)
//   - ones-MFMA denominator: pipe-cosmetic, wall unchanged (round 8)
//   - 2-wave single-buffered blocks: staging serialized, +24us (round 9)
// ---------------------------------------------------------------------------
__global__ __launch_bounds__(256, 2) void attn_kernel(
    const unsigned short* __restrict__ qT,  // [BH][N][128] (pre-scaled by SCALE*log2e)
    const unsigned short* __restrict__ kT,  // [BH][N][128]
    const unsigned short* __restrict__ vg,  // [BH*128][N]
    const unsigned short* __restrict__ xT,  // [B][N][512] residual bf16
    unsigned short* __restrict__ aoT)       // [B][N][512]
{
    __shared__ alignas(16) short Ks[2][64 * 128];   // 16KB/buf: 64 rows x 256B
    __shared__ alignas(16) short Vs[2][64 * 128];   // 16KB/buf: 64 rows x 256B (d,d+64 pairs)

    // bijective XCD swizzle: 512 wgs, 8 XCDs -> 64 consecutive wgs per XCD
    int lin_id = blockIdx.x + 32 * (blockIdx.y + 4 * blockIdx.z);
    int wg = (lin_id & 7) * 64 + (lin_id >> 3);
    const int n0 = (wg & 31) * 128;
    const int h  = (wg >> 5) & 3;
    const int b  = wg >> 7;

    const int bh = b * 4 + h;
    const int tid = threadIdx.x, wid = tid >> 6, l = tid & 63;
    const int lq = l & 31, hi = l >> 5;
    const int wq0 = wid * 32;
    const int swz4 = (l & 15) << 4;             // read-side XOR, bits 4-7
    const unsigned short* Qg = qT + (size_t)bh * NN * 128;
    const unsigned short* Kg = kT + (size_t)bh * NN * 128;
    const unsigned short* Vg = vg + (size_t)bh * 128 * NN;

    // staging geometry: 16 x 1KB chunks per tile per tensor, 4 chunks/wave.
    int kr[4], kc[4], vdd[4], vcc[4], ch[4];
    #pragma unroll
    for (int i = 0; i < 4; ++i) {
        ch[i] = (wid * 4 + i) * 1024;
        int li = ch[i] + l * 16;
        int r = li >> 8, s = (li >> 4) & 15;
        int L = s ^ (r & 15);
        kr[i] = r; kc[i] = L;
        vdd[i] = r + 64 * (L >> 3);
        vcc[i] = L & 7;
    }

    #define STAGE(buf, m0k) do {                                                   \
        _Pragma("unroll")                                                          \
        for (int i = 0; i < 4; ++i) {                                              \
            gld16(&Kg[(size_t)((m0k) + kr[i]) * 128 + kc[i] * 8],                  \
                  (char*)&Ks[buf][0] + ch[i]);                                     \
            gld16(&Vg[(size_t)vdd[i] * NN + (m0k) + vcc[i] * 8],                   \
                  (char*)&Vs[buf][0] + ch[i]);                                     \
        }                                                                          \
    } while (0)

    STAGE(0, 0);

    // ---- Q -> registers (overlaps staging latency) ----
    bf16x8 qr[8];
    #pragma unroll
    for (int dk = 0; dk < 8; ++dk)
        qr[dk] = *(const bf16x8*)&Qg[((size_t)(n0 + wq0 + lq)) * 128 + dk * 16 + hi * 8];

    f32x16 ov[4];
    #pragma unroll
    for (int dt = 0; dt < 4; ++dt)
        #pragma unroll
        for (int r = 0; r < 16; ++r) ov[dt][r] = 0.f;
    float mrun = -1e30f, lrun = 0.f;

    __syncthreads();   // drains vmcnt -> tile 0 staged

    int cur = 0;
    for (int t = 0; t < 64; ++t) {
        if (t < 63) STAGE(cur ^ 1, (t + 1) * 64);   // in flight during compute

        const char* Kc = (const char*)&Ks[cur][0];
        const char* Vc = (const char*)&Vs[cur][0];

        // ---- QK^T (32x32x16): col = q = lq, row k-local = (reg&3)+8*(reg>>2)+4*hi
        f32x16 s0, s1;
        #pragma unroll
        for (int r = 0; r < 16; ++r) { s0[r] = 0.f; s1[r] = 0.f; }
        __builtin_amdgcn_s_setprio(1);
        #pragma unroll
        for (int dk = 0; dk < 8; ++dk) {
            bf16x8 k0 = *(const bf16x8*)(Kc + (lq)      * 256 + ((dk * 32 + hi * 16) ^ swz4));
            bf16x8 k1 = *(const bf16x8*)(Kc + (32 + lq) * 256 + ((dk * 32 + hi * 16) ^ swz4));
            s0 = __builtin_amdgcn_mfma_f32_32x32x16_bf16(k0, qr[dk], s0, 0, 0, 0);
            s1 = __builtin_amdgcn_mfma_f32_32x32x16_bf16(k1, qr[dk], s1, 0, 0, 0);
        }
        __builtin_amdgcn_s_setprio(0);

        // ---- in-register online softmax (log2 domain) ----
        float m8[8];
        #pragma unroll
        for (int r = 0; r < 8; ++r)
            m8[r] = fmaxf(fmaxf(s0[r], s0[r + 8]), fmaxf(s1[r], s1[r + 8]));
        float t0 = fmaxf(fmaxf(m8[0], m8[1]), m8[2]);
        float t1_ = fmaxf(fmaxf(m8[3], m8[4]), m8[5]);
        float t2 = fmaxf(fmaxf(m8[6], m8[7]), t0);
        float pm = fmaxf(t1_, t2);
        pm = fmaxf(pm, __shfl_xor(pm, 32));

        int defer = (pm - mrun) <= THR;
        if (!__all(defer)) {
            float mnew = fmaxf(mrun, pm);
            float corr = fexp2(mrun - mnew);
            lrun *= corr; mrun = mnew;
            #pragma unroll
            for (int dt = 0; dt < 4; ++dt)
                #pragma unroll
                for (int r = 0; r < 16; ++r) ov[dt][r] *= corr;
        }
        float ps = 0.f;
        #pragma unroll
        for (int r = 0; r < 16; ++r) { float e = fexp2(s0[r] - mrun); s0[r] = e; ps += e; }
        #pragma unroll
        for (int r = 0; r < 16; ++r) { float e = fexp2(s1[r] - mrun); s1[r] = e; ps += e; }
        ps += __shfl_xor(ps, 32);
        lrun += ps;

        // ---- P -> bf16 + in-register redistribution (T12) ----
        unsigned int u0[8], u1[8];
        #pragma unroll
        for (int m = 0; m < 8; ++m) {
            u0[m] = cvtpk(s0[2 * m], s0[2 * m + 1]);
            u1[m] = cvtpk(s1[2 * m], s1[2 * m + 1]);
        }
        bf16x8 pf[4];
        #pragma unroll
        for (int kt = 0; kt < 2; ++kt)
            #pragma unroll
            for (int hh = 0; hh < 2; ++hh) {
                const unsigned int* u = kt ? u1 : u0;
                unsigned int w0 = u[4*hh + 0], w2 = u[4*hh + 2];
                unsigned int w1 = u[4*hh + 1], w3 = u[4*hh + 3];
                asm("v_permlane32_swap_b32 %0, %1" : "+v"(w0), "+v"(w2));
                asm("v_permlane32_swap_b32 %0, %1" : "+v"(w1), "+v"(w3));
                unsigned int w[4] = { w0, w1, w2, w3 };
                bf16x8 p; __builtin_memcpy(&p, w, 16);
                pf[kt * 2 + hh] = p;
            }

        // ---- PV (32x32x16): ov[dt] += V^T-tile · P ----
        __builtin_amdgcn_s_setprio(1);
        #pragma unroll
        for (int dt = 0; dt < 4; ++dt)
            #pragma unroll
            for (int kt2 = 0; kt2 < 4; ++kt2) {
                bf16x8 vf = *(const bf16x8*)(Vc + ((dt & 1) * 32 + lq) * 256 +
                                             ((((dt >> 1) * 8 + kt2 * 2 + hi) << 4) ^ swz4));
                ov[dt] = __builtin_amdgcn_mfma_f32_32x32x16_bf16(vf, pf[kt2], ov[dt], 0, 0, 0);
            }
        __builtin_amdgcn_s_setprio(0);

        __syncthreads();   // drains vmcnt (t+1 staged) + guards buffer reuse
        cur ^= 1;
    }
    #undef STAGE

    // ---- epilogue: normalize, add residual, store aoT ----
    float linv = 1.0f / lrun;
    const int n = n0 + wq0 + lq;
    #pragma unroll
    for (int dt = 0; dt < 4; ++dt)
        #pragma unroll
        for (int m = 0; m < 4; ++m) {
            int d = dt * 32 + m * 8 + hi * 4;
            size_t gidx = ((size_t)(b * NN + n)) * CH + h * 128 + d;
            unsigned short xv[4];
            *(ushort4*)xv = *(const ushort4*)&xT[gidx];
            unsigned int w0 = cvtpk(ov[dt][4*m + 0] * linv + bf2f(xv[0]),
                                    ov[dt][4*m + 1] * linv + bf2f(xv[1]));
            unsigned int w1 = cvtpk(ov[dt][4*m + 2] * linv + bf2f(xv[2]),
                                    ov[dt][4*m + 3] * linv + bf2f(xv[3]));
            unsigned long long wv = (unsigned long long)w0 |
                                    ((unsigned long long)w1 << 32);
            *(unsigned long long*)&aoT[gidx] = wv;
        }
}

// ---------------------------------------------------------------------------
extern "C" void kernel_launch(void* const* d_in, const int* in_sizes, int n_in,
                              void* d_out, int out_size, void* d_ws, size_t ws_size,
                              hipStream_t stream) {
    const float* x      = (const float*)d_in[0];
    const float* gamma  = (const float*)d_in[1];
    const float* beta   = (const float*)d_in[2];
    const float* qkv_w  = (const float*)d_in[3];
    const float* qkv_b  = (const float*)d_in[4];
    const float* out_w  = (const float*)d_in[5];
    const float* out_b  = (const float*)d_in[6];
    float* out = (float*)d_out;

    char* ws = (char*)d_ws;
    const size_t SZ = (size_t)BB * CH * NN * 2;     // 16 MB per bf16 tensor
    unsigned short* xnT   = (unsigned short*)(ws);
    unsigned short* xT    = (unsigned short*)(ws + SZ);
    unsigned short* qT    = (unsigned short*)(ws + 2 * SZ);
    unsigned short* kT    = (unsigned short*)(ws + 3 * SZ);
    unsigned short* vbuf  = (unsigned short*)(ws + 4 * SZ);
    unsigned short* aoT   = (unsigned short*)(ws + 5 * SZ);
    unsigned short* wq_bf = (unsigned short*)(ws + 6 * SZ);
    unsigned short* wo_bf = (unsigned short*)(ws + 6 * SZ + (size_t)1536 * 512 * 2);
    float* stats = (float*)(ws + 6 * SZ + (size_t)2048 * 512 * 2);

    hipMemsetAsync(stats, 0, 256 * sizeof(float), stream);
    prep_kernel<<<dim3(1536), 256, 0, stream>>>(qkv_w, out_w, x, wq_bf, wo_bf, stats);
    t1_kernel<<<dim3(NN / 64, CH / 64, BB), 256, 0, stream>>>(
        x, (const float2*)stats, gamma, beta, xnT, xT);
    gemm_kernel<0><<<dim3(NN / 128, 1536 / 128, BB), 256, 0, stream>>>(
        wq_bf, xnT, qkv_b, qT, kT, vbuf, nullptr);
    attn_kernel<<<dim3(NN / 128, NHEADS, BB), 256, 0, stream>>>(qT, kT, vbuf, xT, aoT);
    gemm_kernel<1><<<dim3(NN / 128, CH / 128, BB), 256, 0, stream>>>(
        wo_bf, aoT, out_b, nullptr, nullptr, nullptr, out);
}